// Round 6
// baseline (503.146 us; speedup 1.0000x reference)
//
#include <hip/hip_runtime.h>

#define NQ      3136
#define QPAD    3328
#define MM      65536
#define CC      768
#define MBT     256
#define KTL     64
#define NQB     13
#define KTILES  12
#define TTOT    (NQB * KTILES)   // 156

typedef short bf16x8 __attribute__((ext_vector_type(8)));
typedef float f32x16 __attribute__((ext_vector_type(16)));
typedef unsigned short u16x4 __attribute__((ext_vector_type(4)));

#define GLOAD16(gp, lp) __builtin_amdgcn_global_load_lds( \
    (const __attribute__((address_space(1))) void*)(gp), \
    (__attribute__((address_space(3))) void*)(lp), 16, 0, 0)

__device__ __forceinline__ unsigned short f2bf(float f) {
  unsigned u = __float_as_uint(f);
  u += 0x7fffu + ((u >> 16) & 1u);
  return (unsigned short)(u >> 16);
}

// bank-conflict swizzle (validated r5: conflicts -> 0)
__device__ __forceinline__ int swz(int s, int row) {
  return s ^ (row & 7) ^ ((row >> 3) & 7);
}

// ---------------- prep: per-row sum of squares ----------------
__global__ __launch_bounds__(256) void prep_sumsq(const float* __restrict__ tok,
                                                  const float* __restrict__ bank,
                                                  float* __restrict__ y2,
                                                  float* __restrict__ x2) {
  int row = blockIdx.x * 4 + (threadIdx.x >> 6);
  int lane = threadIdx.x & 63;
  const float* src;
  float* dst;
  bool zero = false;
  if (row < MM) {
    src = bank + (size_t)row * CC;
    dst = y2 + row;
  } else {
    int rx = row - MM;
    if (rx >= QPAD) return;
    zero = (rx >= NQ);
    src = tok + (size_t)(zero ? 0 : rx) * CC;
    dst = x2 + rx;
  }
  float s = 0.f;
#pragma unroll
  for (int p = 0; p < 3; ++p) {
    float4 v = *reinterpret_cast<const float4*>(src + (lane + p * 64) * 4);
    s += v.x * v.x + v.y * v.y + v.z * v.z + v.w * v.w;
  }
#pragma unroll
  for (int m = 32; m >= 1; m >>= 1) s += __shfl_xor(s, m, 64);
  if (lane == 0) *dst = zero ? 0.f : s;
}

// ---------------- convert to bf16, tile-major pre-swizzled ----------------
__global__ __launch_bounds__(256) void convert_bank(const float* __restrict__ bank,
                                                    unsigned short* __restrict__ dst) {
  unsigned idx = blockIdx.x * 256 + threadIdx.x;   // < 65536*96
  unsigned r = idx / 96;
  unsigned cc = idx - r * 96;
  unsigned kt = cc >> 3, s = cc & 7;
  const float* src = bank + (size_t)r * CC + kt * 64 + s * 8;
  float4 a = *reinterpret_cast<const float4*>(src);
  float4 b = *reinterpret_cast<const float4*>(src + 4);
  u16x4 p0, p1;
  p0[0] = f2bf(a.x); p0[1] = f2bf(a.y); p0[2] = f2bf(a.z); p0[3] = f2bf(a.w);
  p1[0] = f2bf(b.x); p1[1] = f2bf(b.y); p1[2] = f2bf(b.z); p1[3] = f2bf(b.w);
  unsigned tile = (r >> 8) * 12 + kt;
  unsigned row = r & 255;
  unsigned short* d = dst + ((size_t)tile << 14) + row * 64 + (swz(s, row) << 3);
  *reinterpret_cast<u16x4*>(d) = p0;
  *reinterpret_cast<u16x4*>(d + 4) = p1;
}

__global__ __launch_bounds__(256) void convert_tok(const float* __restrict__ tok,
                                                   unsigned short* __restrict__ dst) {
  unsigned idx = blockIdx.x * 256 + threadIdx.x;   // < 3328*96
  unsigned r = idx / 96;
  unsigned cc = idx - r * 96;
  unsigned kt = cc >> 3, s = cc & 7;
  unsigned rs = r < NQ ? r : NQ - 1;
  const float* src = tok + (size_t)rs * CC + kt * 64 + s * 8;
  float4 a = *reinterpret_cast<const float4*>(src);
  float4 b = *reinterpret_cast<const float4*>(src + 4);
  u16x4 p0, p1;
  p0[0] = f2bf(a.x); p0[1] = f2bf(a.y); p0[2] = f2bf(a.z); p0[3] = f2bf(a.w);
  p1[0] = f2bf(b.x); p1[1] = f2bf(b.y); p1[2] = f2bf(b.z); p1[3] = f2bf(b.w);
  unsigned tile = (r >> 8) * 12 + kt;
  unsigned row = r & 255;
  unsigned short* d = dst + ((size_t)tile << 14) + row * 64 + (swz(s, row) << 3);
  *reinterpret_cast<u16x4*>(d) = p0;
  *reinterpret_cast<u16x4*>(d + 4) = p1;
}

// ---------------- fused distance-GEMM + per-query top-5 ----------------
// 256 blocks; block b owns mtile b. Sweeps 13 qb x 12 kt in global lockstep order
// so X tiles are L2-shared chip-wide and Y tiles are same-CU L3 re-reads.
// 512 thr (8 waves: 2m x 4q); 256q x 256m tile; 32x32x16 MFMA; 2-phase dbuf.
template <int PRE>
__global__ __launch_bounds__(512, 2) void gemm_topk(
    const float* __restrict__ tok, const float* __restrict__ bank,
    const unsigned short* __restrict__ bswz, const unsigned short* __restrict__ tswz,
    const float* __restrict__ y2g, const float* __restrict__ x2g,
    unsigned* __restrict__ cand) {
  __shared__ __align__(16) char sY[2][MBT * KTL * 2];   // 2 x 32KB
  __shared__ __align__(16) char sX[2][MBT * KTL * 2];   // 2 x 32KB
  __shared__ float y2s[MBT];
  __shared__ unsigned fscratch[MBT * 5];                // 5KB wm-merge scratch

  int b = blockIdx.x;          // == mtile
  int tid = threadIdx.x;
  int lane = tid & 63;
  int wid = tid >> 6;
  int wq = wid & 3;            // 64-query strip
  int wm = wid >> 2;           // 128-row m strip
  int l31 = lane & 31;
  int lhi = lane >> 5;

  float thrp[2];
  auto set_thr = [&](int qb) {
#pragma unroll
    for (int qj = 0; qj < 2; ++qj) {
      int qg = qb * 256 + wq * 64 + qj * 32 + l31;
      int qgc = qg < NQ ? qg : NQ - 1;
      float x2q = x2g[qgc];
      thrp[qj] = 768.f - 3.f * sqrtf(1536.f + 4.f * x2q);
    }
  };

  float lv[2][5];
  unsigned li[2][5];           // mloc within tile (0..255)
#pragma unroll
  for (int qj = 0; qj < 2; ++qj)
#pragma unroll
    for (int s = 0; s < 5; ++s) { lv[qj][s] = 3.4e38f; li[qj][s] = 0u; }

  f32x16 acc[4][2];
#pragma unroll
  for (int mi = 0; mi < 4; ++mi)
#pragma unroll
    for (int qj = 0; qj < 2; ++qj)
#pragma unroll
      for (int e = 0; e < 16; ++e) acc[mi][qj][e] = 0.f;

  auto compute_tile = [&](int bsel) {
#pragma unroll
    for (int ks = 0; ks < 4; ++ks) {
      bf16x8 bfr[2];
#pragma unroll
      for (int qj = 0; qj < 2; ++qj) {
        int row = wq * 64 + qj * 32 + l31;
        int slot = swz(ks * 2 + lhi, row);
        bfr[qj] = *reinterpret_cast<const bf16x8*>(&sX[bsel][row * 128 + slot * 16]);
      }
#pragma unroll
      for (int mi = 0; mi < 4; ++mi) {
        int row = wm * 128 + mi * 32 + l31;
        int slot = swz(ks * 2 + lhi, row);
        bf16x8 af = *reinterpret_cast<const bf16x8*>(&sY[bsel][row * 128 + slot * 16]);
        acc[mi][0] = __builtin_amdgcn_mfma_f32_32x32x16_bf16(af, bfr[0], acc[mi][0], 0, 0, 0);
        acc[mi][1] = __builtin_amdgcn_mfma_f32_32x32x16_bf16(af, bfr[1], acc[mi][1], 0, 0, 0);
      }
    }
  };

  auto insert_pass = [&]() {
#pragma unroll
    for (int mi = 0; mi < 4; ++mi) {
#pragma unroll
      for (int r = 0; r < 16; ++r) {
        int mloc = wm * 128 + mi * 32 + (r & 3) + ((r >> 2) << 3) + (lhi << 2);
        float y2v = y2s[mloc];
#pragma unroll
        for (int qj = 0; qj < 2; ++qj) {
          float d2p = fmaf(-2.f, acc[mi][qj][r], y2v);
          if (d2p < thrp[qj] && d2p < lv[qj][4]) {
            float v = d2p;
            unsigned idv = (unsigned)mloc;
#pragma unroll
            for (int s = 0; s < 5; ++s) {
              bool less = v < lv[qj][s];
              float tv = lv[qj][s]; unsigned ti = li[qj][s];
              if (less) { lv[qj][s] = v; li[qj][s] = idv; v = tv; idv = ti; }
            }
          }
        }
#pragma unroll
        for (int qj = 0; qj < 2; ++qj) acc[mi][qj][r] = 0.f;   // re-zero for next qb
      }
    }
  };

  // pack: 24-bit monotonic key (positive f32 bits >> 8) | 8-bit mloc
  auto flushq = [&](int qb) {
    // union across lhi halves (same q, different acc rows)
#pragma unroll
    for (int qj = 0; qj < 2; ++qj) {
      float ov[5];
      unsigned oi[5];
#pragma unroll
      for (int j = 0; j < 5; ++j) {
        ov[j] = __shfl_xor(lv[qj][j], 32, 64);
        oi[j] = (unsigned)__shfl_xor((int)li[qj][j], 32, 64);
      }
#pragma unroll
      for (int j = 0; j < 5; ++j) {
        float v = ov[j];
        unsigned idv = oi[j];
#pragma unroll
        for (int s = 0; s < 5; ++s) {
          bool less = v < lv[qj][s];
          float tv = lv[qj][s]; unsigned ti = li[qj][s];
          if (less) { lv[qj][s] = v; li[qj][s] = idv; v = tv; idv = ti; }
        }
      }
    }
    unsigned pk[2][5];
#pragma unroll
    for (int qj = 0; qj < 2; ++qj)
#pragma unroll
      for (int s = 0; s < 5; ++s)
        pk[qj][s] = (lv[qj][s] >= 3.0e38f) ? 0xFFFFFFFFu
                    : ((__float_as_uint(fmaxf(lv[qj][s], 0.f)) & 0xFFFFFF00u) | li[qj][s]);
    if (wm == 1 && lhi == 0) {
#pragma unroll
      for (int qj = 0; qj < 2; ++qj) {
        int ql = wq * 64 + qj * 32 + l31;
#pragma unroll
        for (int s = 0; s < 5; ++s) fscratch[ql * 5 + s] = pk[qj][s];
      }
    }
    __syncthreads();
    if (wm == 0 && lhi == 0) {
#pragma unroll
      for (int qj = 0; qj < 2; ++qj) {
        int ql = wq * 64 + qj * 32 + l31;
#pragma unroll
        for (int j = 0; j < 5; ++j) {
          unsigned v = fscratch[ql * 5 + j];
#pragma unroll
          for (int s = 0; s < 5; ++s) {
            unsigned tv = pk[qj][s];
            bool less = v < tv;
            if (less) { pk[qj][s] = v; v = tv; }
          }
        }
        size_t qg = (size_t)(qb * 256 + ql);
        unsigned* cp = cand + (qg * 256 + b) * 5;
#pragma unroll
        for (int s = 0; s < 5; ++s) cp[s] = pk[qj][s];
      }
    }
#pragma unroll
    for (int qj = 0; qj < 2; ++qj)
#pragma unroll
      for (int s = 0; s < 5; ++s) { lv[qj][s] = 3.4e38f; li[qj][s] = 0u; }
  };

  // y2 for this block's fixed mtile: load once
  if (tid < MBT) y2s[tid] = y2g[b * 256 + tid];
  set_thr(0);

  if constexpr (PRE) {
    auto stage = [&](int qb, int kt, int bsel) {
      const char* gY = (const char*)bswz + (((size_t)(b * 12 + kt)) << 15);
      const char* gX = (const char*)tswz + (((size_t)(qb * 12 + kt)) << 15);
      int off = tid * 16;
#pragma unroll
      for (int p = 0; p < 4; ++p) {
        GLOAD16(gY + off + p * 8192, &sY[bsel][off + p * 8192]);
        GLOAD16(gX + off + p * 8192, &sX[bsel][off + p * 8192]);
      }
    };
    stage(0, 0, 0);
    __syncthreads();
    int qbc = 0, ktc = 0;
    for (int t = 0; t < TTOT; ++t) {
      int cur = t & 1;
      if (t + 1 < TTOT) {
        int ktn = ktc + 1, qbn = qbc;
        if (ktn == KTILES) { ktn = 0; qbn++; }
        stage(qbn, ktn, cur ^ 1);
      }
      compute_tile(cur);
      if (ktc == KTILES - 1) {
        insert_pass();
        flushq(qbc);
        if (qbc + 1 < NQB) set_thr(qbc + 1);
      }
      __syncthreads();
      ++ktc; if (ktc == KTILES) { ktc = 0; ++qbc; }
    }
  } else {
    int qbc = 0, ktc = 0;
    for (int t = 0; t < TTOT; ++t) {
      __syncthreads();
      const float* srcY = bank + (size_t)(b * 256) * CC + ktc * KTL;
#pragma unroll 2
      for (int i = 0; i < 8; ++i) {
        int f4 = tid + i * 512;
        int row = f4 >> 4, c = f4 & 15;
        float4 v = *reinterpret_cast<const float4*>(srcY + (size_t)row * CC + c * 4);
        u16x4 p;
        p[0] = f2bf(v.x); p[1] = f2bf(v.y); p[2] = f2bf(v.z); p[3] = f2bf(v.w);
        *reinterpret_cast<u16x4*>(&sY[0][row * 128 + (swz(c >> 1, row) << 4) + ((c & 1) << 3)]) = p;
      }
      int qrow0 = qbc * 256;
#pragma unroll 2
      for (int i = 0; i < 8; ++i) {
        int f4 = tid + i * 512;
        int row = f4 >> 4, c = f4 & 15;
        int srow = qrow0 + row;
        srow = srow < NQ ? srow : NQ - 1;
        float4 v = *reinterpret_cast<const float4*>(tok + (size_t)srow * CC + ktc * KTL + c * 4);
        u16x4 p;
        p[0] = f2bf(v.x); p[1] = f2bf(v.y); p[2] = f2bf(v.z); p[3] = f2bf(v.w);
        *reinterpret_cast<u16x4*>(&sX[0][row * 128 + (swz(c >> 1, row) << 4) + ((c & 1) << 3)]) = p;
      }
      __syncthreads();
      compute_tile(0);
      if (ktc == KTILES - 1) {
        insert_pass();
        __syncthreads();
        flushq(qbc);
        if (qbc + 1 < NQB) set_thr(qbc + 1);
        __syncthreads();
      }
      ++ktc; if (ktc == KTILES) { ktc = 0; ++qbc; }
    }
  }
}

// ---------------- merge candidates, exact fp32 rescoring, final score ----------------
// one wave per query; 256 blocks x 5 packed u32 entries per query
__global__ __launch_bounds__(256) void merge_rescore(
    const float* __restrict__ tok, const float* __restrict__ bank,
    const unsigned* __restrict__ cand, float* __restrict__ out) {
  int q = blockIdx.x * 4 + (threadIdx.x >> 6);
  int lane = threadIdx.x & 63;
  const unsigned* cp = cand + (size_t)q * 1280;
  unsigned e[20];   // 4 blocks x 5 entries per lane
#pragma unroll
  for (int j = 0; j < 20; ++j) e[j] = cp[lane * 20 + j];
  unsigned gids[8];
#pragma unroll
  for (int r = 0; r < 8; ++r) {
    unsigned bv = e[0];
#pragma unroll
    for (int j = 1; j < 20; ++j) bv = e[j] < bv ? e[j] : bv;
    unsigned rv = bv;
    int rl = lane;
#pragma unroll
    for (int m = 32; m >= 1; m >>= 1) {
      unsigned ov = (unsigned)__shfl_xor((int)rv, m, 64);
      int ol = __shfl_xor(rl, m, 64);
      if (ov < rv || (ov == rv && ol < rl)) { rv = ov; rl = ol; }
    }
    unsigned gid = 0;
    if (lane == rl) {
      bool done = false;
#pragma unroll
      for (int j = 0; j < 20; ++j) {
        if (!done && e[j] == rv) {
          gid = (unsigned)((lane * 4 + j / 5) * 256) + (e[j] & 255u);
          e[j] = 0xFFFFFFFFu;
          done = true;
        }
      }
    }
    gids[r] = (unsigned)__shfl((int)gid, rl, 64);
  }
  // exact rescoring: d2 = sum (x - y)^2 in fp32
  float xv[12];
  {
    const float* xp = tok + (size_t)q * CC + lane * 12;
    float4 a = *reinterpret_cast<const float4*>(xp);
    float4 bq = *reinterpret_cast<const float4*>(xp + 4);
    float4 cc4 = *reinterpret_cast<const float4*>(xp + 8);
    xv[0] = a.x; xv[1] = a.y; xv[2] = a.z; xv[3] = a.w;
    xv[4] = bq.x; xv[5] = bq.y; xv[6] = bq.z; xv[7] = bq.w;
    xv[8] = cc4.x; xv[9] = cc4.y; xv[10] = cc4.z; xv[11] = cc4.w;
  }
  float d2e[8];
#pragma unroll
  for (int r = 0; r < 8; ++r) {
    const float* yp = bank + (size_t)(gids[r] & (MM - 1)) * CC + lane * 12;
    float4 a = *reinterpret_cast<const float4*>(yp);
    float4 bq = *reinterpret_cast<const float4*>(yp + 4);
    float4 cc4 = *reinterpret_cast<const float4*>(yp + 8);
    float yv[12];
    yv[0] = a.x; yv[1] = a.y; yv[2] = a.z; yv[3] = a.w;
    yv[4] = bq.x; yv[5] = bq.y; yv[6] = bq.z; yv[7] = bq.w;
    yv[8] = cc4.x; yv[9] = cc4.y; yv[10] = cc4.z; yv[11] = cc4.w;
    float s = 0.f;
#pragma unroll
    for (int e2 = 0; e2 < 12; ++e2) {
      float d = xv[e2] - yv[e2];
      s = fmaf(d, d, s);
    }
#pragma unroll
    for (int m = 32; m >= 1; m >>= 1) s += __shfl_xor(s, m, 64);
    d2e[r] = s;
  }
  // exact top-5 of the 8 rescored candidates
  float d1sq = 0.f, d5sq = 0.f;
#pragma unroll
  for (int r5 = 0; r5 < 5; ++r5) {
    float bv = d2e[0];
    int bj = 0;
#pragma unroll
    for (int j = 1; j < 8; ++j)
      if (d2e[j] < bv) { bv = d2e[j]; bj = j; }
    if (r5 == 0) d1sq = bv;
    if (r5 == 4) d5sq = bv;
#pragma unroll
    for (int j = 0; j < 8; ++j)
      if (j == bj) d2e[j] = 3.4e38f;
  }
  float d1 = sqrtf(fmaxf(d1sq, 0.f));
  float d5 = sqrtf(fmaxf(d5sq, 0.f));
  float gap = fmaxf(d5 - d1, 0.f);
  float sc = d1 * (1.f - expf(-gap));
  if (lane == 0) out[q] = sc;
}

extern "C" void kernel_launch(void* const* d_in, const int* in_sizes, int n_in,
                              void* d_out, int out_size, void* d_ws, size_t ws_size,
                              hipStream_t stream) {
  const float* tok = (const float*)d_in[0];   // 3136x768 fp32
  const float* bank = (const float*)d_in[1];  // 65536x768 fp32
  float* out = (float*)d_out;                 // 3136 fp32
  char* ws = (char*)d_ws;
  float* y2 = (float*)ws;                                   // 256KB
  float* x2 = (float*)(ws + 262144);                        // 13KB
  unsigned* cand = (unsigned*)(ws + 1048576);               // 3328*256*5*4 = 17.04MB
  unsigned short* bswz = (unsigned short*)(ws + 18874368);  // 100.66MB
  unsigned short* tswz = (unsigned short*)(ws + 119537664); // 4.87MB
  const size_t WS_NEED = 124649472ull;

  prep_sumsq<<<(MM + QPAD) / 4, 256, 0, stream>>>(tok, bank, y2, x2);
  if (ws_size >= WS_NEED) {
    convert_bank<<<(MM * 96) / 256, 256, 0, stream>>>(bank, bswz);
    convert_tok<<<(QPAD * 96) / 256, 256, 0, stream>>>(tok, tswz);
    gemm_topk<1><<<256, 512, 0, stream>>>(tok, bank, bswz, tswz, y2, x2, cand);
  } else {
    gemm_topk<0><<<256, 512, 0, stream>>>(tok, bank, bswz, tswz, y2, x2, cand);
  }
  merge_rescore<<<NQ / 4, 256, 0, stream>>>(tok, bank, cand, out);
}

// Round 7
// 499.586 us; speedup vs baseline: 1.0071x; 1.0071x over previous
//
#include <hip/hip_runtime.h>

#define NQ      3136
#define QPAD    3328
#define MM      65536
#define CC      768
#define NQB     13
#define KT2N    24              // K-steps per qb (768/32)
#define TT2     (NQB * KT2N)    // 312

typedef short bf16x8 __attribute__((ext_vector_type(8)));
typedef float f32x16 __attribute__((ext_vector_type(16)));
typedef unsigned short u16x4 __attribute__((ext_vector_type(4)));

#define GLOAD16(gp, lp) __builtin_amdgcn_global_load_lds( \
    (const __attribute__((address_space(1))) void*)(gp), \
    (__attribute__((address_space(3))) void*)(lp), 16, 0, 0)

// barrier with scheduling fences (raw s_barrier has no modeled memory effects)
#define PH_BAR() do { __builtin_amdgcn_sched_barrier(0); \
                      __builtin_amdgcn_s_barrier(); \
                      __builtin_amdgcn_sched_barrier(0); } while (0)

__device__ __forceinline__ unsigned short f2bf(float f) {
  unsigned u = __float_as_uint(f);
  u += 0x7fffu + ((u >> 16) & 1u);
  return (unsigned short)(u >> 16);
}

// 4-slot swizzle: conflict-free (<=2-way) for 32-row strip reads at 8/16-lane granularity
__device__ __forceinline__ int swz4(int s, int row) {
  return s ^ ((row ^ (row >> 2)) & 3);
}

// ---------------- prep: per-row sum of squares ----------------
__global__ __launch_bounds__(256) void prep_sumsq(const float* __restrict__ tok,
                                                  const float* __restrict__ bank,
                                                  float* __restrict__ y2,
                                                  float* __restrict__ x2) {
  int row = blockIdx.x * 4 + (threadIdx.x >> 6);
  int lane = threadIdx.x & 63;
  const float* src;
  float* dst;
  bool zero = false;
  if (row < MM) {
    src = bank + (size_t)row * CC;
    dst = y2 + row;
  } else {
    int rx = row - MM;
    if (rx >= QPAD) return;
    zero = (rx >= NQ);
    src = tok + (size_t)(zero ? 0 : rx) * CC;
    dst = x2 + rx;
  }
  float s = 0.f;
#pragma unroll
  for (int p = 0; p < 3; ++p) {
    float4 v = *reinterpret_cast<const float4*>(src + (lane + p * 64) * 4);
    s += v.x * v.x + v.y * v.y + v.z * v.z + v.w * v.w;
  }
#pragma unroll
  for (int m = 32; m >= 1; m >>= 1) s += __shfl_xor(s, m, 64);
  if (lane == 0) *dst = zero ? 0.f : s;
}

// ---------------- convert to bf16: [tile=(r>>8)*24+kt2][row][4 slots swz4] ------
__global__ __launch_bounds__(256) void convert_bank(const float* __restrict__ bank,
                                                    unsigned short* __restrict__ dst) {
  unsigned idx = blockIdx.x * 256 + threadIdx.x;   // < 65536*96
  unsigned r = idx / 96;
  unsigned g = idx - r * 96;            // global 8-elem slot in row
  unsigned kt2 = g >> 2, s = g & 3;
  const float* src = bank + (size_t)r * CC + g * 8;
  float4 a = *reinterpret_cast<const float4*>(src);
  float4 b = *reinterpret_cast<const float4*>(src + 4);
  u16x4 p0, p1;
  p0[0] = f2bf(a.x); p0[1] = f2bf(a.y); p0[2] = f2bf(a.z); p0[3] = f2bf(a.w);
  p1[0] = f2bf(b.x); p1[1] = f2bf(b.y); p1[2] = f2bf(b.z); p1[3] = f2bf(b.w);
  unsigned tile = (r >> 8) * KT2N + kt2;
  unsigned row = r & 255;
  unsigned short* d = dst + ((size_t)tile << 13) + row * 32 + (swz4(s, row) << 3);
  *reinterpret_cast<u16x4*>(d) = p0;
  *reinterpret_cast<u16x4*>(d + 4) = p1;
}

__global__ __launch_bounds__(256) void convert_tok(const float* __restrict__ tok,
                                                   unsigned short* __restrict__ dst) {
  unsigned idx = blockIdx.x * 256 + threadIdx.x;   // < 3328*96
  unsigned r = idx / 96;
  unsigned g = idx - r * 96;
  unsigned kt2 = g >> 2, s = g & 3;
  unsigned rs = r < NQ ? r : NQ - 1;
  const float* src = tok + (size_t)rs * CC + g * 8;
  float4 a = *reinterpret_cast<const float4*>(src);
  float4 b = *reinterpret_cast<const float4*>(src + 4);
  u16x4 p0, p1;
  p0[0] = f2bf(a.x); p0[1] = f2bf(a.y); p0[2] = f2bf(a.z); p0[3] = f2bf(a.w);
  p1[0] = f2bf(b.x); p1[1] = f2bf(b.y); p1[2] = f2bf(b.z); p1[3] = f2bf(b.w);
  unsigned tile = (r >> 8) * KT2N + kt2;
  unsigned row = r & 255;
  unsigned short* d = dst + ((size_t)tile << 13) + row * 32 + (swz4(s, row) << 3);
  *reinterpret_cast<u16x4*>(d) = p0;
  *reinterpret_cast<u16x4*>(d + 4) = p1;
}

// ---------------- fused distance-GEMM + per-query top-5 ----------------
// 256 blocks, block b owns mtile b; 13 qb x 24 K-steps (BK=32); 8 waves (2m x 4q).
// 4-slot LDS ring per operand, stages issued 3 steps ahead, counted vmcnt(8),
// 2 phases/K-step with raw barriers + setprio around 8-MFMA clusters (T3+T4+T5).
template <int PRE>
__global__ __launch_bounds__(512, 2) void gemm_topk(
    const float* __restrict__ tok, const float* __restrict__ bank,
    const unsigned short* __restrict__ bswz, const unsigned short* __restrict__ tswz,
    const float* __restrict__ y2g, const float* __restrict__ x2g,
    unsigned* __restrict__ cand) {
  __shared__ __align__(16) char sA[4][16384];    // Y ring (bank rows)
  __shared__ __align__(16) char sB[4][16384];    // X ring (queries)
  __shared__ float y2s[256];
  __shared__ unsigned fscratch[256 * 5];

  int b = blockIdx.x;          // == mtile
  int tid = threadIdx.x;
  int lane = tid & 63;
  int wid = tid >> 6;
  int wq = wid & 3;            // 64-query strip
  int wm = wid >> 2;           // 128-row m strip
  int l31 = lane & 31;
  int lhi = lane >> 5;

  // precomputed per-thread LDS byte offsets within a 16KB slot
  int offA[4][2], offB[2][2];
#pragma unroll
  for (int mi = 0; mi < 4; ++mi)
#pragma unroll
    for (int ks = 0; ks < 2; ++ks) {
      int row = wm * 128 + mi * 32 + l31;
      offA[mi][ks] = row * 64 + swz4(ks * 2 + lhi, row) * 16;
    }
#pragma unroll
  for (int qj = 0; qj < 2; ++qj)
#pragma unroll
    for (int ks = 0; ks < 2; ++ks) {
      int row = wq * 64 + qj * 32 + l31;
      offB[qj][ks] = row * 64 + swz4(ks * 2 + lhi, row) * 16;
    }

  float thrp[2];
  auto set_thr = [&](int qb) {
#pragma unroll
    for (int qj = 0; qj < 2; ++qj) {
      int qg = qb * 256 + wq * 64 + qj * 32 + l31;
      int qgc = qg < NQ ? qg : NQ - 1;
      float x2q = x2g[qgc];
      thrp[qj] = 768.f - 3.f * sqrtf(1536.f + 4.f * x2q);
    }
  };

  float lv[2][5];
  unsigned li[2][5];
#pragma unroll
  for (int qj = 0; qj < 2; ++qj)
#pragma unroll
    for (int s = 0; s < 5; ++s) { lv[qj][s] = 3.4e38f; li[qj][s] = 0u; }

  f32x16 acc[4][2];
#pragma unroll
  for (int mi = 0; mi < 4; ++mi)
#pragma unroll
    for (int qj = 0; qj < 2; ++qj)
#pragma unroll
      for (int e = 0; e < 16; ++e) acc[mi][qj][e] = 0.f;

  auto ldB = [&](int ru, bf16x8 bfr[2][2]) {
#pragma unroll
    for (int qj = 0; qj < 2; ++qj)
#pragma unroll
      for (int ks = 0; ks < 2; ++ks)
        bfr[qj][ks] = *reinterpret_cast<const bf16x8*>(&sB[ru][offB[qj][ks]]);
  };
  auto ldA = [&](int ru, bf16x8 af[2][2], int mi0) {
#pragma unroll
    for (int m2 = 0; m2 < 2; ++m2)
#pragma unroll
      for (int ks = 0; ks < 2; ++ks)
        af[m2][ks] = *reinterpret_cast<const bf16x8*>(&sA[ru][offA[mi0 + m2][ks]]);
  };
  auto mm8 = [&](bf16x8 af[2][2], bf16x8 bfr[2][2], int mi0) {
#pragma unroll
    for (int ks = 0; ks < 2; ++ks)
#pragma unroll
      for (int m2 = 0; m2 < 2; ++m2) {
        acc[mi0 + m2][0] = __builtin_amdgcn_mfma_f32_32x32x16_bf16(af[m2][ks], bfr[0][ks], acc[mi0 + m2][0], 0, 0, 0);
        acc[mi0 + m2][1] = __builtin_amdgcn_mfma_f32_32x32x16_bf16(af[m2][ks], bfr[1][ks], acc[mi0 + m2][1], 0, 0, 0);
      }
  };

  auto insert_pass = [&]() {
#pragma unroll
    for (int mi = 0; mi < 4; ++mi) {
#pragma unroll
      for (int r = 0; r < 16; ++r) {
        int mloc = wm * 128 + mi * 32 + (r & 3) + ((r >> 2) << 3) + (lhi << 2);
        float y2v = y2s[mloc];
#pragma unroll
        for (int qj = 0; qj < 2; ++qj) {
          float d2p = fmaf(-2.f, acc[mi][qj][r], y2v);
          if (d2p < thrp[qj] && d2p < lv[qj][4]) {
            float v = d2p;
            unsigned idv = (unsigned)mloc;
#pragma unroll
            for (int s = 0; s < 5; ++s) {
              bool less = v < lv[qj][s];
              float tv = lv[qj][s]; unsigned ti = li[qj][s];
              if (less) { lv[qj][s] = v; li[qj][s] = idv; v = tv; idv = ti; }
            }
          }
        }
#pragma unroll
        for (int qj = 0; qj < 2; ++qj) acc[mi][qj][r] = 0.f;
      }
    }
  };

  auto flushq = [&](int qb) {
#pragma unroll
    for (int qj = 0; qj < 2; ++qj) {
      float ov[5];
      unsigned oi[5];
#pragma unroll
      for (int j = 0; j < 5; ++j) {
        ov[j] = __shfl_xor(lv[qj][j], 32, 64);
        oi[j] = (unsigned)__shfl_xor((int)li[qj][j], 32, 64);
      }
#pragma unroll
      for (int j = 0; j < 5; ++j) {
        float v = ov[j];
        unsigned idv = oi[j];
#pragma unroll
        for (int s = 0; s < 5; ++s) {
          bool less = v < lv[qj][s];
          float tv = lv[qj][s]; unsigned ti = li[qj][s];
          if (less) { lv[qj][s] = v; li[qj][s] = idv; v = tv; idv = ti; }
        }
      }
    }
    unsigned pk[2][5];
#pragma unroll
    for (int qj = 0; qj < 2; ++qj)
#pragma unroll
      for (int s = 0; s < 5; ++s)
        pk[qj][s] = (lv[qj][s] >= 3.0e38f) ? 0xFFFFFFFFu
                    : ((__float_as_uint(fmaxf(lv[qj][s], 0.f)) & 0xFFFFFF00u) | li[qj][s]);
    if (wm == 1 && lhi == 0) {
#pragma unroll
      for (int qj = 0; qj < 2; ++qj) {
        int ql = wq * 64 + qj * 32 + l31;
#pragma unroll
        for (int s = 0; s < 5; ++s) fscratch[ql * 5 + s] = pk[qj][s];
      }
    }
    __syncthreads();
    if (wm == 0 && lhi == 0) {
#pragma unroll
      for (int qj = 0; qj < 2; ++qj) {
        int ql = wq * 64 + qj * 32 + l31;
#pragma unroll
        for (int j = 0; j < 5; ++j) {
          unsigned v = fscratch[ql * 5 + j];
#pragma unroll
          for (int s = 0; s < 5; ++s) {
            unsigned tv = pk[qj][s];
            bool less = v < tv;
            if (less) { pk[qj][s] = v; v = tv; }
          }
        }
        size_t qg = (size_t)(qb * 256 + ql);
        unsigned* cp = cand + (qg * 256 + b) * 5;
#pragma unroll
        for (int s = 0; s < 5; ++s) cp[s] = pk[qj][s];
      }
    }
#pragma unroll
    for (int qj = 0; qj < 2; ++qj)
#pragma unroll
      for (int s = 0; s < 5; ++s) { lv[qj][s] = 3.4e38f; li[qj][s] = 0u; }
  };

  if (tid < 256) y2s[tid] = y2g[b * 256 + tid];
  set_thr(0);

  if constexpr (PRE) {
    // prologue: stage tiles 0,1,2 (A then B per tile; order matters for vmcnt math)
#pragma unroll
    for (int tp = 0; tp < 3; ++tp) {
      const char* gA = (const char*)bswz + ((size_t)(b * KT2N + tp) << 14);
      GLOAD16(gA + (tid << 4), &sA[tp][tid << 4]);
      GLOAD16(gA + 8192 + (tid << 4), &sA[tp][8192 + (tid << 4)]);
      const char* gB = (const char*)tswz + ((size_t)tp << 14);
      GLOAD16(gB + (tid << 4), &sB[tp][tid << 4]);
      GLOAD16(gB + 8192 + (tid << 4), &sB[tp][8192 + (tid << 4)]);
    }
    asm volatile("s_waitcnt vmcnt(8)" ::: "memory");   // tile 0 complete
    PH_BAR();

    int kt3 = 3;            // (t+3) % 24
    int kt2c = 0, qbc = 0;  // current step's kt, qb
    for (int tb = 0; tb < TT2 / 4; ++tb) {
#pragma unroll
      for (int tu = 0; tu < 4; ++tu) {
        int t = tb * 4 + tu;
        int ds = (tu + 3) & 3;       // ring slot for tile t+3
        bf16x8 bfr[2][2], af[2][2];
        // ---- phase 0: read B-frags + A(mi 0,1); stage A(t+3); mfma mi 0,1 ----
        ldB(tu, bfr);
        ldA(tu, af, 0);
        if (t + 3 < TT2) {
          const char* gA = (const char*)bswz + ((size_t)(b * KT2N + kt3) << 14);
          GLOAD16(gA + (tid << 4), &sA[ds][tid << 4]);
          GLOAD16(gA + 8192 + (tid << 4), &sA[ds][8192 + (tid << 4)]);
        }
        PH_BAR();
        __builtin_amdgcn_s_setprio(1);
        mm8(af, bfr, 0);
        __builtin_amdgcn_s_setprio(0);
        PH_BAR();
        // ---- phase 1: read A(mi 2,3); stage B(t+3); mfma mi 2,3 ----
        ldA(tu, af, 2);
        if (t + 3 < TT2) {
          const char* gB = (const char*)tswz + ((size_t)(t + 3) << 14);
          GLOAD16(gB + (tid << 4), &sB[ds][tid << 4]);
          GLOAD16(gB + 8192 + (tid << 4), &sB[ds][8192 + (tid << 4)]);
        }
        PH_BAR();
        __builtin_amdgcn_s_setprio(1);
        mm8(af, bfr, 2);
        __builtin_amdgcn_s_setprio(0);
        // counted wait: <=8 outstanding (tiles t+2,t+3) => tile t+1 staged
        asm volatile("s_waitcnt vmcnt(8)" ::: "memory");
        PH_BAR();
        // ---- bookkeeping / top-k ----
        if (kt2c == 23) {
          insert_pass();
          flushq(qbc);
          if (qbc + 1 < NQB) set_thr(qbc + 1);
          kt2c = 0; ++qbc;
        } else {
          ++kt2c;
        }
        kt3 = (kt3 == 23) ? 0 : kt3 + 1;
      }
    }
  } else {
    // fallback: stage fp32->bf16 by VALU each step, plain 2-barrier loop
    int kt2c = 0, qbc = 0;
    for (int t = 0; t < TT2; ++t) {
      __syncthreads();
#pragma unroll
      for (int j = 0; j < 2; ++j) {
        int u = tid * 2 + j;
        int row = u >> 2, s = u & 3;
        const float* srcA = bank + (size_t)(b * 256 + row) * CC + kt2c * 32 + s * 8;
        float4 a = *reinterpret_cast<const float4*>(srcA);
        float4 b4 = *reinterpret_cast<const float4*>(srcA + 4);
        u16x4 p0, p1;
        p0[0] = f2bf(a.x); p0[1] = f2bf(a.y); p0[2] = f2bf(a.z); p0[3] = f2bf(a.w);
        p1[0] = f2bf(b4.x); p1[1] = f2bf(b4.y); p1[2] = f2bf(b4.z); p1[3] = f2bf(b4.w);
        char* d = &sA[0][row * 64 + swz4(s, row) * 16];
        *reinterpret_cast<u16x4*>(d) = p0;
        *reinterpret_cast<u16x4*>(d + 8) = p1;
        int srow = qbc * 256 + row;
        srow = srow < NQ ? srow : NQ - 1;
        const float* srcB = tok + (size_t)srow * CC + kt2c * 32 + s * 8;
        a = *reinterpret_cast<const float4*>(srcB);
        b4 = *reinterpret_cast<const float4*>(srcB + 4);
        p0[0] = f2bf(a.x); p0[1] = f2bf(a.y); p0[2] = f2bf(a.z); p0[3] = f2bf(a.w);
        p1[0] = f2bf(b4.x); p1[1] = f2bf(b4.y); p1[2] = f2bf(b4.z); p1[3] = f2bf(b4.w);
        d = &sB[0][row * 64 + swz4(s, row) * 16];
        *reinterpret_cast<u16x4*>(d) = p0;
        *reinterpret_cast<u16x4*>(d + 8) = p1;
      }
      __syncthreads();
      bf16x8 bfr[2][2], af[2][2];
      ldB(0, bfr);
      ldA(0, af, 0);
      mm8(af, bfr, 0);
      ldA(0, af, 2);
      mm8(af, bfr, 2);
      if (kt2c == 23) {
        __syncthreads();
        insert_pass();
        flushq(qbc);
        if (qbc + 1 < NQB) set_thr(qbc + 1);
        kt2c = 0; ++qbc;
      } else {
        ++kt2c;
      }
    }
  }
}

// ---------------- merge candidates, exact fp32 rescoring, final score ----------------
__global__ __launch_bounds__(256) void merge_rescore(
    const float* __restrict__ tok, const float* __restrict__ bank,
    const unsigned* __restrict__ cand, float* __restrict__ out) {
  int q = blockIdx.x * 4 + (threadIdx.x >> 6);
  int lane = threadIdx.x & 63;
  const unsigned* cp = cand + (size_t)q * 1280;
  unsigned e[20];   // 4 blocks x 5 entries per lane
#pragma unroll
  for (int j = 0; j < 20; ++j) e[j] = cp[lane * 20 + j];
  unsigned gids[8];
#pragma unroll
  for (int r = 0; r < 8; ++r) {
    unsigned bv = e[0];
#pragma unroll
    for (int j = 1; j < 20; ++j) bv = e[j] < bv ? e[j] : bv;
    unsigned rv = bv;
    int rl = lane;
#pragma unroll
    for (int m = 32; m >= 1; m >>= 1) {
      unsigned ov = (unsigned)__shfl_xor((int)rv, m, 64);
      int ol = __shfl_xor(rl, m, 64);
      if (ov < rv || (ov == rv && ol < rl)) { rv = ov; rl = ol; }
    }
    unsigned gid = 0;
    if (lane == rl) {
      bool done = false;
#pragma unroll
      for (int j = 0; j < 20; ++j) {
        if (!done && e[j] == rv) {
          gid = (unsigned)((lane * 4 + j / 5) * 256) + (e[j] & 255u);
          e[j] = 0xFFFFFFFFu;
          done = true;
        }
      }
    }
    gids[r] = (unsigned)__shfl((int)gid, rl, 64);
  }
  float xv[12];
  {
    const float* xp = tok + (size_t)q * CC + lane * 12;
    float4 a = *reinterpret_cast<const float4*>(xp);
    float4 bq = *reinterpret_cast<const float4*>(xp + 4);
    float4 cc4 = *reinterpret_cast<const float4*>(xp + 8);
    xv[0] = a.x; xv[1] = a.y; xv[2] = a.z; xv[3] = a.w;
    xv[4] = bq.x; xv[5] = bq.y; xv[6] = bq.z; xv[7] = bq.w;
    xv[8] = cc4.x; xv[9] = cc4.y; xv[10] = cc4.z; xv[11] = cc4.w;
  }
  float d2e[8];
#pragma unroll
  for (int r = 0; r < 8; ++r) {
    const float* yp = bank + (size_t)(gids[r] & (MM - 1)) * CC + lane * 12;
    float4 a = *reinterpret_cast<const float4*>(yp);
    float4 bq = *reinterpret_cast<const float4*>(yp + 4);
    float4 cc4 = *reinterpret_cast<const float4*>(yp + 8);
    float yv[12];
    yv[0] = a.x; yv[1] = a.y; yv[2] = a.z; yv[3] = a.w;
    yv[4] = bq.x; yv[5] = bq.y; yv[6] = bq.z; yv[7] = bq.w;
    yv[8] = cc4.x; yv[9] = cc4.y; yv[10] = cc4.z; yv[11] = cc4.w;
    float s = 0.f;
#pragma unroll
    for (int e2 = 0; e2 < 12; ++e2) {
      float d = xv[e2] - yv[e2];
      s = fmaf(d, d, s);
    }
#pragma unroll
    for (int m = 32; m >= 1; m >>= 1) s += __shfl_xor(s, m, 64);
    d2e[r] = s;
  }
  float d1sq = 0.f, d5sq = 0.f;
#pragma unroll
  for (int r5 = 0; r5 < 5; ++r5) {
    float bv = d2e[0];
    int bj = 0;
#pragma unroll
    for (int j = 1; j < 8; ++j)
      if (d2e[j] < bv) { bv = d2e[j]; bj = j; }
    if (r5 == 0) d1sq = bv;
    if (r5 == 4) d5sq = bv;
#pragma unroll
    for (int j = 0; j < 8; ++j)
      if (j == bj) d2e[j] = 3.4e38f;
  }
  float d1 = sqrtf(fmaxf(d1sq, 0.f));
  float d5 = sqrtf(fmaxf(d5sq, 0.f));
  float gap = fmaxf(d5 - d1, 0.f);
  float sc = d1 * (1.f - expf(-gap));
  if (lane == 0) out[q] = sc;
}

extern "C" void kernel_launch(void* const* d_in, const int* in_sizes, int n_in,
                              void* d_out, int out_size, void* d_ws, size_t ws_size,
                              hipStream_t stream) {
  const float* tok = (const float*)d_in[0];   // 3136x768 fp32
  const float* bank = (const float*)d_in[1];  // 65536x768 fp32
  float* out = (float*)d_out;                 // 3136 fp32
  char* ws = (char*)d_ws;
  float* y2 = (float*)ws;                                   // 256KB
  float* x2 = (float*)(ws + 262144);                        // 13KB
  unsigned* cand = (unsigned*)(ws + 1048576);               // 3328*256*5*4 = 17.04MB
  unsigned short* bswz = (unsigned short*)(ws + 18874368);  // 100.66MB
  unsigned short* tswz = (unsigned short*)(ws + 119537664); // 4.87MB
  const size_t WS_NEED = 124649472ull;

  prep_sumsq<<<(MM + QPAD) / 4, 256, 0, stream>>>(tok, bank, y2, x2);
  if (ws_size >= WS_NEED) {
    convert_bank<<<(MM * 96) / 256, 256, 0, stream>>>(bank, bswz);
    convert_tok<<<(QPAD * 96) / 256, 256, 0, stream>>>(tok, tswz);
    gemm_topk<1><<<256, 512, 0, stream>>>(tok, bank, bswz, tswz, y2, x2, cand);
  } else {
    gemm_topk<0><<<256, 512, 0, stream>>>(tok, bank, bswz, tswz, y2, x2, cand);
  }
  merge_rescore<<<NQ / 4, 256, 0, stream>>>(tok, bank, cand, out);
}